// Round 5
// baseline (414.998 us; speedup 1.0000x reference)
//
#include <hip/hip_runtime.h>
#include <cmath>

#define Bdim 8
#define Cdim 768
#define Kdim 256
#define Ndim 4096
#define NT 64      // tokens per block in kernel 1
#define KC 16      // C-chunk staged in LDS (3-deep buffered)
#define NCHUNK (Cdim / KC)
#define CB2 4      // c-rows per block in kernel 2
#define NCOPY 4    // replicated LDS accumulators in kernel 2

// direct global->LDS DMA, 16B per lane, wave-uniform LDS base
typedef __attribute__((address_space(1))) const unsigned int g_u32;
typedef __attribute__((address_space(3))) unsigned int l_u32;
__device__ __forceinline__ void gload16(const void* g, void* l) {
    __builtin_amdgcn_global_load_lds((g_u32*)g, (l_u32*)l, 16, 0, 0);
}

// Prep: per batch b — centroid inverse norms + zero cnt.
__global__ __launch_bounds__(256) void prep_kernel(
    const float* __restrict__ cents,   // (B,C,K)
    float* __restrict__ invc,          // (B,K)
    int*   __restrict__ cnt)           // (B,K)
{
    __shared__ float red[4][Kdim];
    const int tid = threadIdx.x;
    const int b = blockIdx.x;
    const float* cb = cents + (size_t)b * Cdim * Kdim;
    const int q = tid & 63;
    const int g = tid >> 6;
    float4 ss = make_float4(0.f, 0.f, 0.f, 0.f);
    for (int r = g; r < Cdim; r += 4) {
        float4 v = *(const float4*)(cb + (size_t)r * Kdim + q * 4);
        ss.x = fmaf(v.x, v.x, ss.x); ss.y = fmaf(v.y, v.y, ss.y);
        ss.z = fmaf(v.z, v.z, ss.z); ss.w = fmaf(v.w, v.w, ss.w);
    }
    *(float4*)&red[g][q * 4] = ss;
    __syncthreads();
    float s = red[0][tid] + red[1][tid] + red[2][tid] + red[3][tid];
    invc[b * Kdim + tid] = 1.f / fmaxf(sqrtf(s), 1e-12f);
    cnt[b * Kdim + tid] = 0;
}

// Kernel 1: per (b, n-tile of 64): fp32 cos GEMM (8x8/thread), sigmoid,
// first-win argmax, scatter winner into pre-zeroed simOut.
// Staging: global_load_lds DMA, 3-deep buffer, counted vmcnt (never 0 in loop),
// raw s_barrier. NO other global loads in the main loop (exact vmcnt math).
__global__ __launch_bounds__(256) void sim_argmax_kernel(
    const float* __restrict__ x,        // (B,C,N)
    const float* __restrict__ cents,    // (B,C,K)
    const float* __restrict__ alpha_p,
    const float* __restrict__ beta_p,
    const float* __restrict__ invc,     // (B,K)
    float* __restrict__ simOut,         // (B,K,N), pre-zeroed
    float* __restrict__ wArr,           // (B,N)
    int*   __restrict__ kArr,           // (B,N)
    int*   __restrict__ cnt)            // (B,K), pre-zeroed
{
    __shared__ float sc[3][KC][Kdim];   // 48 KB centroid chunks
    __shared__ float sx[3][KC][NT];     // 12 KB x chunks
    __shared__ float px[4][NT];         // 1 KB
    __shared__ float invxS[NT];
    __shared__ float bval[32][NT];      // 8 KB
    __shared__ int   bidx[32][NT];      // 8 KB

    const int tid  = threadIdx.x;
    const int lane = tid & 63;
    const int wv   = tid >> 6;          // wave id 0..3
    const int b    = blockIdx.x >> 6;
    const int n0   = (blockIdx.x & 63) * NT;
    const float* xb = x     + (size_t)b * Cdim * Ndim;
    const float* cb = cents + (size_t)b * Cdim * Kdim;

    const int kb = (tid >> 3) * 8;
    const int nb = (tid & 7) * 8;

    float acc[8][8];
    #pragma unroll
    for (int i = 0; i < 8; ++i)
        #pragma unroll
        for (int j = 0; j < 8; ++j) acc[i][j] = 0.f;

    float xn2p = 0.f;

    // STAGE(chunk, buf): wave wv DMAs sc rows 4wv..4wv+3 and its sx quarter.
    // Exactly 5 global_load_lds (vmcnt ops) per wave per STAGE.
    #define STAGE(ch, bf)                                                     \
        do {                                                                  \
            const int c0_ = (ch) * KC;                                        \
            _Pragma("unroll")                                                 \
            for (int i_ = 0; i_ < 4; ++i_) {                                  \
                int r_ = wv * 4 + i_;                                         \
                gload16(cb + (size_t)(c0_ + r_) * Kdim + lane * 4,            \
                        &sc[bf][r_][0]);                                      \
            }                                                                 \
            gload16(xb + (size_t)(c0_ + wv * 4 + (lane >> 4)) * Ndim          \
                       + n0 + (lane & 15) * 4,                                \
                    &sx[bf][wv * 4][0]);                                      \
        } while (0)

    #define COMPUTE(cur)                                                      \
        do {                                                                  \
            _Pragma("unroll")                                                 \
            for (int r_ = 0; r_ < 4; ++r_) {                                  \
                float v = sx[cur][(tid >> 6) * 4 + r_][tid & 63];             \
                xn2p = fmaf(v, v, xn2p);                                      \
            }                                                                 \
            _Pragma("unroll")                                                 \
            for (int r = 0; r < KC; ++r) {                                    \
                float a0[8], b0[8];                                           \
                *(float4*)(a0)     = *(const float4*)&sc[cur][r][kb];         \
                *(float4*)(a0 + 4) = *(const float4*)&sc[cur][r][kb + 4];     \
                *(float4*)(b0)     = *(const float4*)&sx[cur][r][nb];         \
                *(float4*)(b0 + 4) = *(const float4*)&sx[cur][r][nb + 4];     \
                _Pragma("unroll")                                             \
                for (int i = 0; i < 8; ++i)                                   \
                    _Pragma("unroll")                                         \
                    for (int j = 0; j < 8; ++j)                               \
                        acc[i][j] = fmaf(a0[i], b0[j], acc[i][j]);            \
            }                                                                 \
        } while (0)

    STAGE(0, 0);
    STAGE(1, 1);

    for (int t = 0; t < NCHUNK - 1; ++t) {
        // own chunk-t loads done; t+1 (and t+2 after issue) stay in flight
        asm volatile("s_waitcnt vmcnt(5)" ::: "memory");
        __builtin_amdgcn_s_barrier();
        if (t + 2 < NCHUNK) STAGE(t + 2, (t + 2) % 3);
        COMPUTE(t % 3);
    }
    asm volatile("s_waitcnt vmcnt(0)" ::: "memory");
    __builtin_amdgcn_s_barrier();
    COMPUTE((NCHUNK - 1) % 3);

    #undef STAGE
    #undef COMPUTE

    px[tid >> 6][tid & 63] = xn2p;
    __syncthreads();
    if (tid < NT) {
        float s = px[0][tid] + px[1][tid] + px[2][tid] + px[3][tid];
        invxS[tid] = 1.f / fmaxf(sqrtf(s), 1e-12f);
    }
    __syncthreads();

    const float alpha = alpha_p[0];
    const float beta  = beta_p[0];
    float invcv[8];
    *(float4*)(invcv)     = *(const float4*)&invc[b * Kdim + kb];
    *(float4*)(invcv + 4) = *(const float4*)&invc[b * Kdim + kb + 4];

    // per-thread argmax over its 8 k (ascending k, strict > = first-win),
    // sigmoid in fp32 per-k exactly like the reference
    #pragma unroll
    for (int j = 0; j < 8; ++j) {
        int n = nb + j;
        float ix = invxS[n];
        float best = -1.f; int bkk = 0;
        #pragma unroll
        for (int i = 0; i < 8; ++i) {
            float cosv = acc[i][j] * invcv[i] * ix;
            float s = 1.f / (1.f + expf(-(beta + alpha * cosv)));
            if (s > best) { best = s; bkk = kb + i; }
        }
        bval[tid >> 3][n] = best;
        bidx[tid >> 3][n] = bkk;
    }
    __syncthreads();
    if (tid < NT) {
        int n = tid;
        float best = -1.f; int bkk = 0;
        for (int g = 0; g < 32; ++g) {   // ascending k-groups = first-win
            float v = bval[g][n];
            if (v > best) { best = v; bkk = bidx[g][n]; }
        }
        int gn = b * Ndim + n0 + n;
        wArr[gn] = best;
        kArr[gn] = bkk;
        simOut[((size_t)(b * Kdim + bkk)) * Ndim + n0 + n] = best;
        atomicAdd(&cnt[b * Kdim + bkk], 1);
    }
}

// Kernel 2: per (b, 4 c-rows): stream all N tokens; 4-way replicated LDS
// accumulators (copy = tid&3) cut same-address + bank RMW serialization;
// w/k read straight from global (L2-warm). Fused epilogue.
__global__ __launch_bounds__(256) void agg_kernel(
    const float* __restrict__ x,        // (B,C,N)
    const float* __restrict__ cents,    // (B,C,K)
    const float* __restrict__ wArr,
    const int*   __restrict__ kArr,
    const int*   __restrict__ cnt,
    float* __restrict__ hyp)            // (B,K,C)
{
    __shared__ float accs[NCOPY][CB2][Kdim + 1];   // 16.4 KB
    const int tid = threadIdx.x;
    const int b  = blockIdx.x / (Cdim / CB2);
    const int c0 = (blockIdx.x % (Cdim / CB2)) * CB2;

    for (int i = tid; i < NCOPY * CB2 * (Kdim + 1); i += 256) ((float*)accs)[i] = 0.f;
    __syncthreads();

    const int cp = tid & 3;
    const float* xb = x + ((size_t)b * Cdim + c0) * Ndim;
    #pragma unroll
    for (int i = 0; i < 4; ++i) {
        int n = (tid + i * 256) * 4;
        int4   kv = *(const int4*)&kArr[b * Ndim + n];
        float4 w4 = *(const float4*)&wArr[b * Ndim + n];
        float4 xv[CB2];
        #pragma unroll
        for (int r = 0; r < CB2; ++r)
            xv[r] = *(const float4*)&xb[(size_t)r * Ndim + n];
        #pragma unroll
        for (int r = 0; r < CB2; ++r) {
            atomicAdd(&accs[cp][r][kv.x], w4.x * xv[r].x);
            atomicAdd(&accs[cp][r][kv.y], w4.y * xv[r].y);
            atomicAdd(&accs[cp][r][kv.z], w4.z * xv[r].z);
            atomicAdd(&accs[cp][r][kv.w], w4.w * xv[r].w);
        }
    }
    __syncthreads();

    // fused epilogue: hyp[b][k][c0+cl] = (sum copies + ct)/(cnt+1)
    const int cl = tid & 3;
    #pragma unroll
    for (int it = 0; it < 4; ++it) {
        int k = (tid >> 2) + it * 64;
        float s = accs[0][cl][k] + accs[1][cl][k] + accs[2][cl][k] + accs[3][cl][k];
        float num = s + cents[((size_t)b * Cdim + c0 + cl) * Kdim + k];
        hyp[((size_t)(b * Kdim + k)) * Cdim + c0 + cl] = num / (float)(cnt[b * Kdim + k] + 1);
    }
}

extern "C" void kernel_launch(void* const* d_in, const int* in_sizes, int n_in,
                              void* d_out, int out_size, void* d_ws, size_t ws_size,
                              hipStream_t stream)
{
    const float* x     = (const float*)d_in[0];
    const float* cents = (const float*)d_in[1];
    const float* alpha = (const float*)d_in[2];
    const float* beta  = (const float*)d_in[3];

    float* hyp    = (float*)d_out;                                    // (B,K,C)
    float* simOut = (float*)d_out + (size_t)Bdim * Kdim * Cdim;       // (B,K,N)

    float* wArr = (float*)d_ws;
    int*   kArr = (int*)((char*)d_ws + (size_t)Bdim * Ndim * sizeof(float));
    int*   cnt  = (int*)((char*)d_ws + 2 * (size_t)Bdim * Ndim * sizeof(float));
    float* invc = (float*)((char*)d_ws + 2 * (size_t)Bdim * Ndim * sizeof(float)
                                       + (size_t)Bdim * Kdim * sizeof(int));

    hipMemsetAsync(simOut, 0, (size_t)Bdim * Kdim * Ndim * sizeof(float), stream);

    prep_kernel<<<dim3(Bdim), dim3(256), 0, stream>>>(cents, invc, cnt);
    sim_argmax_kernel<<<dim3(Bdim * (Ndim / NT)), dim3(256), 0, stream>>>(
        x, cents, alpha, beta, invc, simOut, wArr, kArr, cnt);
    agg_kernel<<<dim3(Bdim * (Cdim / CB2)), dim3(256), 0, stream>>>(
        x, cents, wArr, kArr, cnt, hyp);
}

// Round 7
// 315.749 us; speedup vs baseline: 1.3143x; 1.3143x over previous
//
#include <hip/hip_runtime.h>
#include <cmath>

#define Bdim 8
#define Cdim 768
#define Kdim 256
#define Ndim 4096
#define NT 64      // tokens per block in kernel 1
#define KC2 32     // C-chunk per MFMA stage (3-buffered)
#define NCH (Cdim / KC2)   // 24
#define CB2 4      // c-rows per block in kernel 2
#define NCOPY 4    // replicated LDS accumulators in kernel 2

typedef __bf16 bf16x8 __attribute__((ext_vector_type(8)));
typedef short  s16x8  __attribute__((ext_vector_type(8)));
typedef float  f32x4  __attribute__((ext_vector_type(4)));
union U8 { s16x8 s; bf16x8 b; };

// direct global->LDS DMA, 16B per lane, wave-uniform LDS base
typedef __attribute__((address_space(1))) const unsigned int g_u32;
typedef __attribute__((address_space(3))) unsigned int l_u32;
__device__ __forceinline__ void gload16(const void* g, void* l) {
    __builtin_amdgcn_global_load_lds((g_u32*)g, (l_u32*)l, 16, 0, 0);
}

// three-level bf16 split, RNE at each level; v = h + m + l + eps, |eps| <= 2^-27 |v|
__device__ __forceinline__ void split3(float v, short& h, short& m, short& l) {
    unsigned u = __float_as_uint(v);
    unsigned th = u + 0x7FFFu + ((u >> 16) & 1u);
    h = (short)(th >> 16);
    float r1 = v - __uint_as_float(th & 0xFFFF0000u);      // exact
    unsigned u1 = __float_as_uint(r1);
    unsigned tm = u1 + 0x7FFFu + ((u1 >> 16) & 1u);
    m = (short)(tm >> 16);
    float r2 = r1 - __uint_as_float(tm & 0xFFFF0000u);     // exact
    unsigned u2 = __float_as_uint(r2);
    unsigned tl = u2 + 0x7FFFu + ((u2 >> 16) & 1u);
    l = (short)(tl >> 16);
}

// Prep: per batch b — centroid inverse norms (fp32, exact) + zero cnt.
__global__ __launch_bounds__(256) void prep_kernel(
    const float* __restrict__ cents, float* __restrict__ invc, int* __restrict__ cnt)
{
    __shared__ float red[4][Kdim];
    const int tid = threadIdx.x;
    const int b = blockIdx.x;
    const float* cb = cents + (size_t)b * Cdim * Kdim;
    const int q = tid & 63, g = tid >> 6;
    float4 ss = make_float4(0.f, 0.f, 0.f, 0.f);
    for (int r = g; r < Cdim; r += 4) {
        float4 v = *(const float4*)(cb + (size_t)r * Kdim + q * 4);
        ss.x = fmaf(v.x, v.x, ss.x); ss.y = fmaf(v.y, v.y, ss.y);
        ss.z = fmaf(v.z, v.z, ss.z); ss.w = fmaf(v.w, v.w, ss.w);
    }
    *(float4*)&red[g][q * 4] = ss;
    __syncthreads();
    float s = red[0][tid] + red[1][tid] + red[2][tid] + red[3][tid];
    invc[b * Kdim + tid] = 1.f / fmaxf(sqrtf(s), 1e-12f);
    cnt[b * Kdim + tid] = 0;
}

// Cvt: centroids -> split-3 bf16 planes in MFMA-fragment layout
// plane[(b*96 + c/8)*256 + k][8]: 8 consecutive c per 16B record.
__global__ __launch_bounds__(256) void cvt_kernel(
    const float* __restrict__ cents, short* __restrict__ centH,
    short* __restrict__ centM, short* __restrict__ centL)
{
    const int k = threadIdx.x;
    const int bc = blockIdx.x;                    // b*96 + c8
    const float* src = cents + ((size_t)(bc / 96) * Cdim + (size_t)(bc % 96) * 8) * Kdim + k;
    s16x8 H, M, L;
    #pragma unroll
    for (int e = 0; e < 8; ++e) {
        short h, m, l;
        split3(src[(size_t)e * Kdim], h, m, l);   // coalesced across lanes (k)
        H[e] = h; M[e] = m; L[e] = l;
    }
    ((s16x8*)centH)[(size_t)bc * 256 + k] = H;    // 16B coalesced stores
    ((s16x8*)centM)[(size_t)bc * 256 + k] = M;
    ((s16x8*)centL)[(size_t)bc * 256 + k] = L;
}

// Kernel 1: per (b, n-tile of 64): cos via split-3 bf16 MFMA, 6 passes
// (hh in acc; hm,mh,hl,lh,mm in acc2 -> accumulation noise ~7e-9 in cos,
// below the fp32-VALU kernel that passed). fp32 sigmoid/argmax epilogue,
// scatter winner into pre-zeroed simOut. Wave w owns k in [w*64, w*64+64).
__global__ __launch_bounds__(256) void sim_mfma_kernel(
    const float* __restrict__ x,        // (B,C,N) fp32
    const short* __restrict__ centH,
    const short* __restrict__ centM,
    const short* __restrict__ centL,
    const float* __restrict__ alpha_p,
    const float* __restrict__ beta_p,
    const float* __restrict__ invc,     // (B,K) fp32
    float* __restrict__ simOut,         // (B,K,N), pre-zeroed
    float* __restrict__ wArr,
    int*   __restrict__ kArr,
    int*   __restrict__ cnt)
{
    __shared__ __align__(16) float sxf[3][KC2][NT];  // 24 KB fp32 x chunks
    __shared__ float invcS[Kdim];
    __shared__ float px[4][NT];
    __shared__ float invxS[NT];
    __shared__ float bwv[4][NT];
    __shared__ int   bwk[4][NT];

    const int tid  = threadIdx.x;
    const int lane = tid & 63;
    const int w    = tid >> 6;          // wave id: k-range [w*64, w*64+64)
    const int q    = lane >> 4;         // 0..3
    const int c15  = lane & 15;
    const int b    = blockIdx.x >> 6;
    const int n0   = (blockIdx.x & 63) * NT;
    const float* xb = x + (size_t)b * Cdim * Ndim;

    invcS[tid] = invc[b * Kdim + tid];
    const float alpha = alpha_p[0];
    const float beta  = beta_p[0];

    f32x4 acc[4][4], acc2[4][4];
    #pragma unroll
    for (int i = 0; i < 4; ++i)
        #pragma unroll
        for (int j = 0; j < 4; ++j) {
            acc[i][j]  = (f32x4){0.f, 0.f, 0.f, 0.f};
            acc2[i][j] = (f32x4){0.f, 0.f, 0.f, 0.f};
        }

    float xn2p = 0.f;

    // exactly 2 DMA (vmcnt) ops per wave per STAGE
    #define STAGE(t_) do {                                                    \
        const int bf_ = (t_) % 3; const int c0_ = (t_) * KC2;                 \
        _Pragma("unroll")                                                     \
        for (int i_ = 0; i_ < 2; ++i_)                                        \
            gload16(xb + (size_t)(c0_ + w * 8 + i_ * 4 + q) * Ndim            \
                       + n0 + c15 * 4,                                        \
                    &sxf[bf_][w * 8 + i_ * 4][0]);                            \
    } while (0)

    STAGE(0);
    STAGE(1);

    const s16x8* cHb = (const s16x8*)centH + ((size_t)b * 96) * 256;
    const s16x8* cMb = (const s16x8*)centM + ((size_t)b * 96) * 256;
    const s16x8* cLb = (const s16x8*)centL + ((size_t)b * 96) * 256;

    for (int t = 0; t < NCH; ++t) {
        // retire everything except STAGE(t+1)'s 2 newest; chunk t ready
        asm volatile("s_waitcnt vmcnt(2)" ::: "memory");
        __builtin_amdgcn_s_barrier();
        __builtin_amdgcn_sched_barrier(0);

        const int cur = t % 3;

        // A fragments (12 16B loads, L2-resident planes), before next STAGE
        U8 aH[4], aM[4], aL[4];
        {
            const size_t rowb = ((size_t)(t * 4 + q)) * 256 + w * 64 + c15;
            #pragma unroll
            for (int kf = 0; kf < 4; ++kf) {
                aH[kf].s = cHb[rowb + kf * 16];
                aM[kf].s = cMb[rowb + kf * 16];
                aL[kf].s = cLb[rowb + kf * 16];
            }
        }
        if (t + 2 < NCH) STAGE(t + 2);

        // x-norm partials (rows w*8..w*8+7, col = lane)
        #pragma unroll
        for (int r = 0; r < 8; ++r) {
            float v = sxf[cur][w * 8 + r][lane];
            xn2p = fmaf(v, v, xn2p);
        }

        // B fragments: split fp32 tile -> h/m/l bf16 in-register
        U8 bH[4], bM[4], bL[4];
        #pragma unroll
        for (int nf = 0; nf < 4; ++nf) {
            #pragma unroll
            for (int e = 0; e < 8; ++e) {
                short h, m, l;
                split3(sxf[cur][q * 8 + e][nf * 16 + c15], h, m, l);
                bH[nf].s[e] = h; bM[nf].s[e] = m; bL[nf].s[e] = l;
            }
        }

        // 6 passes x 16 fragment-MFMAs, pass-major
        #pragma unroll
        for (int kf = 0; kf < 4; ++kf)
            #pragma unroll
            for (int nf = 0; nf < 4; ++nf)
                acc[kf][nf] = __builtin_amdgcn_mfma_f32_16x16x32_bf16(
                    aH[kf].b, bH[nf].b, acc[kf][nf], 0, 0, 0);
        #pragma unroll
        for (int kf = 0; kf < 4; ++kf)
            #pragma unroll
            for (int nf = 0; nf < 4; ++nf)
                acc2[kf][nf] = __builtin_amdgcn_mfma_f32_16x16x32_bf16(
                    aH[kf].b, bM[nf].b, acc2[kf][nf], 0, 0, 0);
        #pragma unroll
        for (int kf = 0; kf < 4; ++kf)
            #pragma unroll
            for (int nf = 0; nf < 4; ++nf)
                acc2[kf][nf] = __builtin_amdgcn_mfma_f32_16x16x32_bf16(
                    aM[kf].b, bH[nf].b, acc2[kf][nf], 0, 0, 0);
        #pragma unroll
        for (int kf = 0; kf < 4; ++kf)
            #pragma unroll
            for (int nf = 0; nf < 4; ++nf)
                acc2[kf][nf] = __builtin_amdgcn_mfma_f32_16x16x32_bf16(
                    aH[kf].b, bL[nf].b, acc2[kf][nf], 0, 0, 0);
        #pragma unroll
        for (int kf = 0; kf < 4; ++kf)
            #pragma unroll
            for (int nf = 0; nf < 4; ++nf)
                acc2[kf][nf] = __builtin_amdgcn_mfma_f32_16x16x32_bf16(
                    aL[kf].b, bH[nf].b, acc2[kf][nf], 0, 0, 0);
        #pragma unroll
        for (int kf = 0; kf < 4; ++kf)
            #pragma unroll
            for (int nf = 0; nf < 4; ++nf)
                acc2[kf][nf] = __builtin_amdgcn_mfma_f32_16x16x32_bf16(
                    aM[kf].b, bM[nf].b, acc2[kf][nf], 0, 0, 0);
    }
    #undef STAGE

    __syncthreads();
    px[w][lane] = xn2p;
    __syncthreads();
    if (tid < NT) {
        float s = px[0][tid] + px[1][tid] + px[2][tid] + px[3][tid];
        invxS[tid] = 1.f / fmaxf(sqrtf(s), 1e-12f);
    }
    __syncthreads();

    // epilogue: cos -> sigmoid -> argmax (first-win = min-k on ties)
    // D layout: row(k_local) = q*4 + reg, col(n) = c15
    #pragma unroll
    for (int nf = 0; nf < 4; ++nf) {
        const float ivx = invxS[nf * 16 + c15];
        float best = -1.f; int bk = 0;
        #pragma unroll
        for (int kf = 0; kf < 4; ++kf) {
            float4 ic = *(const float4*)&invcS[w * 64 + kf * 16 + q * 4];
            #pragma unroll
            for (int r = 0; r < 4; ++r) {
                float cosv = (acc[kf][nf][r] + acc2[kf][nf][r]) * ((const float*)&ic)[r] * ivx;
                float s = 1.f / (1.f + expf(-(beta + alpha * cosv)));
                int k = w * 64 + kf * 16 + q * 4 + r;
                if (s > best) { best = s; bk = k; }   // ascending k scan
            }
        }
        // reduce across q-groups (lanes l, l^16, l^32, l^48 share n)
        #pragma unroll
        for (int off = 16; off < 64; off <<= 1) {
            float ov = __shfl_xor(best, off);
            int   ok = __shfl_xor(bk, off);
            if (ov > best || (ov == best && ok < bk)) { best = ov; bk = ok; }
        }
        if (q == 0) { bwv[w][nf * 16 + c15] = best; bwk[w][nf * 16 + c15] = bk; }
    }
    __syncthreads();
    if (tid < NT) {
        float best = -1.f; int bk = 0;
        #pragma unroll
        for (int g = 0; g < 4; ++g) {    // ascending waves = ascending k
            float v = bwv[g][tid];
            if (v > best) { best = v; bk = bwk[g][tid]; }
        }
        int gn = b * Ndim + n0 + tid;
        wArr[gn] = best;
        kArr[gn] = bk;
        simOut[((size_t)(b * Kdim + bk)) * Ndim + n0 + tid] = best;
        atomicAdd(&cnt[b * Kdim + bk], 1);
    }
}

// Kernel 2: per (b, 4 c-rows): stream all N tokens; 4-way replicated LDS
// accumulators; w/k straight from global (L2-warm). Fused epilogue.
__global__ __launch_bounds__(256) void agg_kernel(
    const float* __restrict__ x, const float* __restrict__ cents,
    const float* __restrict__ wArr, const int* __restrict__ kArr,
    const int* __restrict__ cnt, float* __restrict__ hyp)
{
    __shared__ float accs[NCOPY][CB2][Kdim + 1];
    const int tid = threadIdx.x;
    const int b  = blockIdx.x / (Cdim / CB2);
    const int c0 = (blockIdx.x % (Cdim / CB2)) * CB2;

    for (int i = tid; i < NCOPY * CB2 * (Kdim + 1); i += 256) ((float*)accs)[i] = 0.f;
    __syncthreads();

    const int cp = tid & 3;
    const float* xb = x + ((size_t)b * Cdim + c0) * Ndim;
    #pragma unroll
    for (int i = 0; i < 4; ++i) {
        int n = (tid + i * 256) * 4;
        int4   kv = *(const int4*)&kArr[b * Ndim + n];
        float4 w4 = *(const float4*)&wArr[b * Ndim + n];
        float4 xv[CB2];
        #pragma unroll
        for (int r = 0; r < CB2; ++r)
            xv[r] = *(const float4*)&xb[(size_t)r * Ndim + n];
        #pragma unroll
        for (int r = 0; r < CB2; ++r) {
            atomicAdd(&accs[cp][r][kv.x], w4.x * xv[r].x);
            atomicAdd(&accs[cp][r][kv.y], w4.y * xv[r].y);
            atomicAdd(&accs[cp][r][kv.z], w4.z * xv[r].z);
            atomicAdd(&accs[cp][r][kv.w], w4.w * xv[r].w);
        }
    }
    __syncthreads();

    const int cl = tid & 3;
    #pragma unroll
    for (int it = 0; it < 4; ++it) {
        int k = (tid >> 2) + it * 64;
        float s = accs[0][cl][k] + accs[1][cl][k] + accs[2][cl][k] + accs[3][cl][k];
        float num = s + cents[((size_t)b * Cdim + c0 + cl) * Kdim + k];
        hyp[((size_t)(b * Kdim + k)) * Cdim + c0 + cl] = num / (float)(cnt[b * Kdim + k] + 1);
    }
}

extern "C" void kernel_launch(void* const* d_in, const int* in_sizes, int n_in,
                              void* d_out, int out_size, void* d_ws, size_t ws_size,
                              hipStream_t stream)
{
    const float* x     = (const float*)d_in[0];
    const float* cents = (const float*)d_in[1];
    const float* alpha = (const float*)d_in[2];
    const float* beta  = (const float*)d_in[3];

    float* hyp    = (float*)d_out;                                    // (B,K,C)
    float* simOut = (float*)d_out + (size_t)Bdim * Kdim * Cdim;       // (B,K,N)

    char* ws = (char*)d_ws;
    float* wArr  = (float*)(ws);                                 // 131072 B
    int*   kArr  = (int*)  (ws + 131072);                        // 131072 B
    int*   cnt   = (int*)  (ws + 262144);                        // 8192 B
    float* invc  = (float*)(ws + 270336);                        // 8192 B
    short* centH = (short*)(ws + 278528);                        // 3145728 B
    short* centM = (short*)(ws + 278528 + 3145728);              // 3145728 B
    short* centL = (short*)(ws + 278528 + 2 * 3145728);          // 3145728 B

    hipMemsetAsync(simOut, 0, (size_t)Bdim * Kdim * Ndim * sizeof(float), stream);

    prep_kernel<<<dim3(Bdim), dim3(256), 0, stream>>>(cents, invc, cnt);
    cvt_kernel<<<dim3(Bdim * 96), dim3(256), 0, stream>>>(cents, centH, centM, centL);
    sim_mfma_kernel<<<dim3(Bdim * (Ndim / NT)), dim3(256), 0, stream>>>(
        x, centH, centM, centL, alpha, beta, invc, simOut, wArr, kArr, cnt);
    agg_kernel<<<dim3(Bdim * (Cdim / CB2)), dim3(256), 0, stream>>>(
        x, cents, wArr, kArr, cnt, hyp);
}

// Round 8
// 273.014 us; speedup vs baseline: 1.5201x; 1.1565x over previous
//
#include <hip/hip_runtime.h>
#include <cmath>

#define Bdim 8
#define Cdim 768
#define Kdim 256
#define Ndim 4096
#define NT 64      // tokens per block in kernel 1
#define KC2 32     // C-chunk per MFMA stage (3-buffered)
#define NCH (Cdim / KC2)   // 24
#define CB2 4      // c-rows per block in kernel 2
#define NCOPY 4    // replicated LDS accumulators in kernel 2

typedef __bf16 bf16x8 __attribute__((ext_vector_type(8)));
typedef short  s16x8  __attribute__((ext_vector_type(8)));
typedef float  f32x4  __attribute__((ext_vector_type(4)));
union U8 { s16x8 s; bf16x8 b; };

// direct global->LDS DMA, 16B per lane, wave-uniform LDS base
typedef __attribute__((address_space(1))) const unsigned int g_u32;
typedef __attribute__((address_space(3))) unsigned int l_u32;
__device__ __forceinline__ void gload16(const void* g, void* l) {
    __builtin_amdgcn_global_load_lds((g_u32*)g, (l_u32*)l, 16, 0, 0);
}

// three-level bf16 split, RNE at each level; v = h + m + l + eps, |eps| <= 2^-27 |v|
__device__ __forceinline__ void split3(float v, short& h, short& m, short& l) {
    unsigned u = __float_as_uint(v);
    unsigned th = u + 0x7FFFu + ((u >> 16) & 1u);
    h = (short)(th >> 16);
    float r1 = v - __uint_as_float(th & 0xFFFF0000u);      // exact
    unsigned u1 = __float_as_uint(r1);
    unsigned tm = u1 + 0x7FFFu + ((u1 >> 16) & 1u);
    m = (short)(tm >> 16);
    float r2 = r1 - __uint_as_float(tm & 0xFFFF0000u);     // exact
    unsigned u2 = __float_as_uint(r2);
    unsigned tl = u2 + 0x7FFFu + ((u2 >> 16) & 1u);
    l = (short)(tl >> 16);
}

// Prep: per batch b — centroid inverse norms (fp32, exact) + zero cnt.
__global__ __launch_bounds__(256) void prep_kernel(
    const float* __restrict__ cents, float* __restrict__ invc, int* __restrict__ cnt)
{
    __shared__ float red[4][Kdim];
    const int tid = threadIdx.x;
    const int b = blockIdx.x;
    const float* cb = cents + (size_t)b * Cdim * Kdim;
    const int q = tid & 63, g = tid >> 6;
    float4 ss = make_float4(0.f, 0.f, 0.f, 0.f);
    for (int r = g; r < Cdim; r += 4) {
        float4 v = *(const float4*)(cb + (size_t)r * Kdim + q * 4);
        ss.x = fmaf(v.x, v.x, ss.x); ss.y = fmaf(v.y, v.y, ss.y);
        ss.z = fmaf(v.z, v.z, ss.z); ss.w = fmaf(v.w, v.w, ss.w);
    }
    *(float4*)&red[g][q * 4] = ss;
    __syncthreads();
    float s = red[0][tid] + red[1][tid] + red[2][tid] + red[3][tid];
    invc[b * Kdim + tid] = 1.f / fmaxf(sqrtf(s), 1e-12f);
    cnt[b * Kdim + tid] = 0;
}

// Cvt: centroids -> split-3 bf16 planes in MFMA-fragment layout
// plane[(b*96 + c/8)*256 + k][8]: 8 consecutive c per 16B record.
__global__ __launch_bounds__(256) void cvt_kernel(
    const float* __restrict__ cents, short* __restrict__ centH,
    short* __restrict__ centM, short* __restrict__ centL)
{
    const int k = threadIdx.x;
    const int bc = blockIdx.x;                    // b*96 + c8
    const float* src = cents + ((size_t)(bc / 96) * Cdim + (size_t)(bc % 96) * 8) * Kdim + k;
    s16x8 H, M, L;
    #pragma unroll
    for (int e = 0; e < 8; ++e) {
        short h, m, l;
        split3(src[(size_t)e * Kdim], h, m, l);   // coalesced across lanes (k)
        H[e] = h; M[e] = m; L[e] = l;
    }
    ((s16x8*)centH)[(size_t)bc * 256 + k] = H;    // 16B coalesced stores
    ((s16x8*)centM)[(size_t)bc * 256 + k] = M;
    ((s16x8*)centL)[(size_t)bc * 256 + k] = L;
}

// Kernel 1: per (b, n-tile of 64): cos via split-3 bf16 MFMA, 6 passes
// (hh, hm, mh, hl, lh, mm) into ONE accumulator (noise ~1.5e-8 cos, safe).
// __launch_bounds__(256,2): 2 waves/SIMD is the grid cap anyway; this frees
// the full ~256-VGPR budget so acc + 24 fragments stay live (no remat).
__global__ __launch_bounds__(256, 2) void sim_mfma_kernel(
    const float* __restrict__ x,        // (B,C,N) fp32
    const short* __restrict__ centH,
    const short* __restrict__ centM,
    const short* __restrict__ centL,
    const float* __restrict__ alpha_p,
    const float* __restrict__ beta_p,
    const float* __restrict__ invc,     // (B,K) fp32
    float* __restrict__ simOut,         // (B,K,N), pre-zeroed
    float* __restrict__ wArr,
    int*   __restrict__ kArr,
    int*   __restrict__ cnt)
{
    __shared__ __align__(16) float sxf[3][KC2][NT];  // 24 KB fp32 x chunks
    __shared__ float invcS[Kdim];
    __shared__ float px[4][NT];
    __shared__ float invxS[NT];
    __shared__ float bwv[4][NT];
    __shared__ int   bwk[4][NT];

    const int tid  = threadIdx.x;
    const int lane = tid & 63;
    const int w    = tid >> 6;          // wave id: k-range [w*64, w*64+64)
    const int q    = lane >> 4;         // 0..3
    const int c15  = lane & 15;
    const int b    = blockIdx.x >> 6;
    const int n0   = (blockIdx.x & 63) * NT;
    const float* xb = x + (size_t)b * Cdim * Ndim;

    invcS[tid] = invc[b * Kdim + tid];
    const float alpha = alpha_p[0];
    const float beta  = beta_p[0];

    f32x4 acc[4][4];
    #pragma unroll
    for (int i = 0; i < 4; ++i)
        #pragma unroll
        for (int j = 0; j < 4; ++j) acc[i][j] = (f32x4){0.f, 0.f, 0.f, 0.f};

    float xn2p = 0.f;

    // exactly 2 DMA (vmcnt) ops per wave per STAGE
    #define STAGE(t_) do {                                                    \
        const int bf_ = (t_) % 3; const int c0_ = (t_) * KC2;                 \
        _Pragma("unroll")                                                     \
        for (int i_ = 0; i_ < 2; ++i_)                                        \
            gload16(xb + (size_t)(c0_ + w * 8 + i_ * 4 + q) * Ndim            \
                       + n0 + c15 * 4,                                        \
                    &sxf[bf_][w * 8 + i_ * 4][0]);                            \
    } while (0)

    STAGE(0);
    STAGE(1);

    const s16x8* cHb = (const s16x8*)centH + ((size_t)b * 96) * 256;
    const s16x8* cMb = (const s16x8*)centM + ((size_t)b * 96) * 256;
    const s16x8* cLb = (const s16x8*)centL + ((size_t)b * 96) * 256;

    for (int t = 0; t < NCH; ++t) {
        // retire everything except STAGE(t+1)'s 2 newest; chunk t ready
        asm volatile("s_waitcnt vmcnt(2)" ::: "memory");
        __builtin_amdgcn_s_barrier();
        __builtin_amdgcn_sched_barrier(0);

        const int cur = t % 3;

        // A fragments (12 16B loads, L2/L3-resident planes), before next STAGE
        U8 aH[4], aM[4], aL[4];
        {
            const size_t rowb = ((size_t)(t * 4 + q)) * 256 + w * 64 + c15;
            #pragma unroll
            for (int kf = 0; kf < 4; ++kf) {
                aH[kf].s = cHb[rowb + kf * 16];
                aM[kf].s = cMb[rowb + kf * 16];
                aL[kf].s = cLb[rowb + kf * 16];
            }
        }
        if (t + 2 < NCH) STAGE(t + 2);

        // x-norm partials (rows w*8..w*8+7, col = lane)
        #pragma unroll
        for (int r = 0; r < 8; ++r) {
            float v = sxf[cur][w * 8 + r][lane];
            xn2p = fmaf(v, v, xn2p);
        }

        // B fragments: split fp32 tile -> h/m/l bf16 in-register
        U8 bH[4], bM[4], bL[4];
        #pragma unroll
        for (int nf = 0; nf < 4; ++nf) {
            #pragma unroll
            for (int e = 0; e < 8; ++e) {
                short h, m, l;
                split3(sxf[cur][q * 8 + e][nf * 16 + c15], h, m, l);
                bH[nf].s[e] = h; bM[nf].s[e] = m; bL[nf].s[e] = l;
            }
        }

        // 6 passes x 16 fragment-MFMAs, pass-major, single accumulator
        #pragma unroll
        for (int kf = 0; kf < 4; ++kf)
            #pragma unroll
            for (int nf = 0; nf < 4; ++nf)
                acc[kf][nf] = __builtin_amdgcn_mfma_f32_16x16x32_bf16(
                    aH[kf].b, bH[nf].b, acc[kf][nf], 0, 0, 0);
        #pragma unroll
        for (int kf = 0; kf < 4; ++kf)
            #pragma unroll
            for (int nf = 0; nf < 4; ++nf)
                acc[kf][nf] = __builtin_amdgcn_mfma_f32_16x16x32_bf16(
                    aH[kf].b, bM[nf].b, acc[kf][nf], 0, 0, 0);
        #pragma unroll
        for (int kf = 0; kf < 4; ++kf)
            #pragma unroll
            for (int nf = 0; nf < 4; ++nf)
                acc[kf][nf] = __builtin_amdgcn_mfma_f32_16x16x32_bf16(
                    aM[kf].b, bH[nf].b, acc[kf][nf], 0, 0, 0);
        #pragma unroll
        for (int kf = 0; kf < 4; ++kf)
            #pragma unroll
            for (int nf = 0; nf < 4; ++nf)
                acc[kf][nf] = __builtin_amdgcn_mfma_f32_16x16x32_bf16(
                    aH[kf].b, bL[nf].b, acc[kf][nf], 0, 0, 0);
        #pragma unroll
        for (int kf = 0; kf < 4; ++kf)
            #pragma unroll
            for (int nf = 0; nf < 4; ++nf)
                acc[kf][nf] = __builtin_amdgcn_mfma_f32_16x16x32_bf16(
                    aL[kf].b, bH[nf].b, acc[kf][nf], 0, 0, 0);
        #pragma unroll
        for (int kf = 0; kf < 4; ++kf)
            #pragma unroll
            for (int nf = 0; nf < 4; ++nf)
                acc[kf][nf] = __builtin_amdgcn_mfma_f32_16x16x32_bf16(
                    aM[kf].b, bM[nf].b, acc[kf][nf], 0, 0, 0);
    }
    #undef STAGE

    __syncthreads();
    px[w][lane] = xn2p;
    __syncthreads();
    if (tid < NT) {
        float s = px[0][tid] + px[1][tid] + px[2][tid] + px[3][tid];
        invxS[tid] = 1.f / fmaxf(sqrtf(s), 1e-12f);
    }
    __syncthreads();

    // epilogue: cos -> sigmoid -> argmax (first-win = min-k on ties)
    // D layout: row(k_local) = q*4 + reg, col(n) = c15
    #pragma unroll
    for (int nf = 0; nf < 4; ++nf) {
        const float ivx = invxS[nf * 16 + c15];
        float best = -1.f; int bk = 0;
        #pragma unroll
        for (int kf = 0; kf < 4; ++kf) {
            float4 ic = *(const float4*)&invcS[w * 64 + kf * 16 + q * 4];
            #pragma unroll
            for (int r = 0; r < 4; ++r) {
                float cosv = acc[kf][nf][r] * ((const float*)&ic)[r] * ivx;
                float s = 1.f / (1.f + expf(-(beta + alpha * cosv)));
                int k = w * 64 + kf * 16 + q * 4 + r;
                if (s > best) { best = s; bk = k; }   // ascending k scan
            }
        }
        // reduce across q-groups (lanes l, l^16, l^32, l^48 share n)
        #pragma unroll
        for (int off = 16; off < 64; off <<= 1) {
            float ov = __shfl_xor(best, off);
            int   ok = __shfl_xor(bk, off);
            if (ov > best || (ov == best && ok < bk)) { best = ov; bk = ok; }
        }
        if (q == 0) { bwv[w][nf * 16 + c15] = best; bwk[w][nf * 16 + c15] = bk; }
    }
    __syncthreads();
    if (tid < NT) {
        float best = -1.f; int bk = 0;
        #pragma unroll
        for (int g = 0; g < 4; ++g) {    // ascending waves = ascending k
            float v = bwv[g][tid];
            if (v > best) { best = v; bk = bwk[g][tid]; }
        }
        int gn = b * Ndim + n0 + tid;
        wArr[gn] = best;
        kArr[gn] = bk;
        simOut[((size_t)(b * Kdim + bk)) * Ndim + n0 + tid] = best;
        atomicAdd(&cnt[b * Kdim + bk], 1);
    }
}

// Kernel 2: per (b, 4 c-rows): stream all N tokens; 4-way replicated LDS
// accumulators; w/k straight from global (L2-warm). Fused epilogue.
__global__ __launch_bounds__(256) void agg_kernel(
    const float* __restrict__ x, const float* __restrict__ cents,
    const float* __restrict__ wArr, const int* __restrict__ kArr,
    const int* __restrict__ cnt, float* __restrict__ hyp)
{
    __shared__ float accs[NCOPY][CB2][Kdim + 1];
    const int tid = threadIdx.x;
    const int b  = blockIdx.x / (Cdim / CB2);
    const int c0 = (blockIdx.x % (Cdim / CB2)) * CB2;

    for (int i = tid; i < NCOPY * CB2 * (Kdim + 1); i += 256) ((float*)accs)[i] = 0.f;
    __syncthreads();

    const int cp = tid & 3;
    const float* xb = x + ((size_t)b * Cdim + c0) * Ndim;
    #pragma unroll
    for (int i = 0; i < 4; ++i) {
        int n = (tid + i * 256) * 4;
        int4   kv = *(const int4*)&kArr[b * Ndim + n];
        float4 w4 = *(const float4*)&wArr[b * Ndim + n];
        float4 xv[CB2];
        #pragma unroll
        for (int r = 0; r < CB2; ++r)
            xv[r] = *(const float4*)&xb[(size_t)r * Ndim + n];
        #pragma unroll
        for (int r = 0; r < CB2; ++r) {
            atomicAdd(&accs[cp][r][kv.x], w4.x * xv[r].x);
            atomicAdd(&accs[cp][r][kv.y], w4.y * xv[r].y);
            atomicAdd(&accs[cp][r][kv.z], w4.z * xv[r].z);
            atomicAdd(&accs[cp][r][kv.w], w4.w * xv[r].w);
        }
    }
    __syncthreads();

    const int cl = tid & 3;
    #pragma unroll
    for (int it = 0; it < 4; ++it) {
        int k = (tid >> 2) + it * 64;
        float s = accs[0][cl][k] + accs[1][cl][k] + accs[2][cl][k] + accs[3][cl][k];
        float num = s + cents[((size_t)b * Cdim + c0 + cl) * Kdim + k];
        hyp[((size_t)(b * Kdim + k)) * Cdim + c0 + cl] = num / (float)(cnt[b * Kdim + k] + 1);
    }
}

extern "C" void kernel_launch(void* const* d_in, const int* in_sizes, int n_in,
                              void* d_out, int out_size, void* d_ws, size_t ws_size,
                              hipStream_t stream)
{
    const float* x     = (const float*)d_in[0];
    const float* cents = (const float*)d_in[1];
    const float* alpha = (const float*)d_in[2];
    const float* beta  = (const float*)d_in[3];

    float* hyp    = (float*)d_out;                                    // (B,K,C)
    float* simOut = (float*)d_out + (size_t)Bdim * Kdim * Cdim;       // (B,K,N)

    char* ws = (char*)d_ws;
    float* wArr  = (float*)(ws);                                 // 131072 B
    int*   kArr  = (int*)  (ws + 131072);                        // 131072 B
    int*   cnt   = (int*)  (ws + 262144);                        // 8192 B
    float* invc  = (float*)(ws + 270336);                        // 8192 B
    short* centH = (short*)(ws + 278528);                        // 3145728 B
    short* centM = (short*)(ws + 278528 + 3145728);              // 3145728 B
    short* centL = (short*)(ws + 278528 + 2 * 3145728);          // 3145728 B

    hipMemsetAsync(simOut, 0, (size_t)Bdim * Kdim * Ndim * sizeof(float), stream);

    prep_kernel<<<dim3(Bdim), dim3(256), 0, stream>>>(cents, invc, cnt);
    cvt_kernel<<<dim3(Bdim * 96), dim3(256), 0, stream>>>(cents, centH, centM, centL);
    sim_mfma_kernel<<<dim3(Bdim * (Ndim / NT)), dim3(256), 0, stream>>>(
        x, centH, centM, centL, alpha, beta, invc, simOut, wArr, kArr, cnt);
    agg_kernel<<<dim3(Bdim * (Cdim / CB2)), dim3(256), 0, stream>>>(
        x, cents, wArr, kArr, cnt, hyp);
}